// Round 1
// baseline (1165.273 us; speedup 1.0000x reference)
//
#include <hip/hip_runtime.h>
#include <hip/hip_bf16.h>
#include <math.h>

// GGNN: N=50000 nodes, E=400000 edges, G=64 graphs, IN=64, OUT=128, 4 etypes, 8 steps.
// R6: aggregate-first restructuring.
//   a[v] = sum_t W_t * s_{v,t} + sum_t cnt[v,t]*bs_t,  s_{v,t} = sum_{e:dst=v,et=t} h[src]
//   - CSR keyed by (dst, etype): 200000 segments, 2-level scan
//   - k_agg_gemm: per 128-node tile, gather s (regs, fp32) -> LDS fp16 -> K=512 MFMA
//     (4 etype chunks, B-frags straight from global/L1), cnt*bs bias epilogue -> ab fp16
//   - k_gates_gemm: 6 groups ([gi|gh], A = ab for 0..2 / hb for 3..5), O is 768 cols
//   - k_gru unchanged math, new offsets (gh at 384)
//   - Wh table never materialized; gather reads 12.8 MB hb (L2-resident) instead of
//     51.2 MB O region

#define NN 50000
#define NE 400000
#define NG 64
#define IND 64
#define OD 128
#define NN4 (NN * 4)
#define LDO 768   // O row (halfs): 0..383 = gi (r,z,n), 384..767 = gh (r,z,n)
#define RC 8      // readout chunks per graph

typedef _Float16 f16x8 __attribute__((ext_vector_type(8)));
typedef _Float16 f16x4 __attribute__((ext_vector_type(4)));
typedef _Float16 f16x2 __attribute__((ext_vector_type(2)));
typedef float f32x4 __attribute__((ext_vector_type(4)));

__device__ inline unsigned short f2h(float x) {
    _Float16 hv = (_Float16)x;
    unsigned short u;
    __builtin_memcpy(&u, &hv, 2);
    return u;
}

// ---------------- fp32 -> fp16 weight conversion ----------------
__global__ void k_cvt(const float* __restrict__ s, unsigned short* __restrict__ d, int n) {
    int i = blockIdx.x * 256 + threadIdx.x;
    if (i < n) d[i] = f2h(s[i]);
}

// ---------------- init h = [node_features | 0] (fp32 + fp16 shadow) ----------------
__global__ void k_init_h(const float* __restrict__ nf, float* __restrict__ h,
                         unsigned short* __restrict__ hb) {
    int i = blockIdx.x * 256 + threadIdx.x;
    if (i >= NN * OD) return;
    int n = i >> 7, d = i & 127;
    float v = (d < IND) ? nf[n * IND + d] : 0.f;
    h[i] = v;
    hb[i] = f2h(v);
}

// ---------------- (dst, etype) CSR build: 200000 segments ----------------
__global__ void k_count(const int* __restrict__ dst, const int* __restrict__ et,
                        int* __restrict__ deg4) {
    int e = blockIdx.x * 256 + threadIdx.x;
    if (e < NE) atomicAdd(&deg4[dst[e] * 4 + et[e]], 1);
}

__global__ void k_scan1(const int* __restrict__ deg, int* __restrict__ rowp,
                        int* __restrict__ bsum, int n) {
    __shared__ int buf[1024];
    int tid = threadIdx.x;
    int i = blockIdx.x * 1024 + tid;
    int v = (i < n) ? deg[i] : 0;
    buf[tid] = v;
    __syncthreads();
    for (int off = 1; off < 1024; off <<= 1) {
        int t = (tid >= off) ? buf[tid - off] : 0;
        __syncthreads();
        buf[tid] += t;
        __syncthreads();
    }
    if (i < n) rowp[i + 1] = buf[tid];
    if (tid == 1023) bsum[blockIdx.x] = buf[tid];
}

__global__ void k_scan2(int* __restrict__ bsum, int nb) {
    __shared__ int buf[256];
    int tid = threadIdx.x;
    int v = (tid < nb) ? bsum[tid] : 0;
    buf[tid] = v;
    __syncthreads();
    for (int off = 1; off < 256; off <<= 1) {
        int t = (tid >= off) ? buf[tid - off] : 0;
        __syncthreads();
        buf[tid] += t;
        __syncthreads();
    }
    if (tid < nb) bsum[tid] = buf[tid] - v;   // exclusive
}

__global__ void k_scan3(const int* __restrict__ deg, const int* __restrict__ bsum,
                        int* __restrict__ rowp, int* __restrict__ cursor, int n) {
    int i = blockIdx.x * 256 + threadIdx.x;
    if (i >= n) return;
    int incl = rowp[i + 1] + bsum[i >> 10];
    rowp[i + 1] = incl;
    cursor[i] = incl - deg[i];
    if (i == 0) rowp[0] = 0;
}

__global__ void k_fill(const int* __restrict__ src, const int* __restrict__ dst,
                       const int* __restrict__ et, int* __restrict__ cursor,
                       int* __restrict__ esrc) {
    int e = blockIdx.x * 256 + threadIdx.x;
    if (e < NE) {
        int pos = atomicAdd(&cursor[dst[e] * 4 + et[e]], 1);
        esrc[pos] = src[e];
    }
}

// ---------------- graph CSR build (by graph id), for readout ----------------
__global__ void k_gcount(const int* __restrict__ gid, int* __restrict__ gdeg) {
    __shared__ int c[NG];
    int tid = threadIdx.x;
    if (tid < NG) c[tid] = 0;
    __syncthreads();
    int n = blockIdx.x * 1024 + tid;
    if (n < NN) atomicAdd(&c[gid[n]], 1);
    __syncthreads();
    if (tid < NG && c[tid] > 0) atomicAdd(&gdeg[tid], c[tid]);
}

__global__ void k_gscan(const int* __restrict__ gdeg, int* __restrict__ growp,
                        int* __restrict__ gcur) {
    __shared__ int buf[NG];
    int tid = threadIdx.x;
    int v = gdeg[tid];
    buf[tid] = v;
    __syncthreads();
    for (int off = 1; off < NG; off <<= 1) {
        int t = (tid >= off) ? buf[tid - off] : 0;
        __syncthreads();
        buf[tid] += t;
        __syncthreads();
    }
    growp[tid + 1] = buf[tid];
    gcur[tid] = buf[tid] - v;
    if (tid == 0) growp[0] = 0;
}

__global__ void k_gfill(const int* __restrict__ gid, int* __restrict__ gcur,
                        int* __restrict__ nlist) {
    __shared__ int lcnt[NG];
    __shared__ int lbase[NG];
    int tid = threadIdx.x;
    if (tid < NG) lcnt[tid] = 0;
    __syncthreads();
    int n = blockIdx.x * 1024 + tid;
    int g = -1, rank = 0;
    if (n < NN) { g = gid[n]; rank = atomicAdd(&lcnt[g], 1); }
    __syncthreads();
    if (tid < NG && lcnt[tid] > 0) lbase[tid] = atomicAdd(&gcur[tid], lcnt[tid]);
    __syncthreads();
    if (n < NN) nlist[lbase[g] + rank] = n;
}

// ---------------- fused aggregate + K=512 GEMM: ab = sum_t s_t @ W_t^T + cnt*bs ------
// Block: 256 thr (4 waves), tile 128 dst nodes.
// Gather: thread pair per node row; s_{v,t} accumulated fp32 in regs (64 dims/lane).
// Per t: regs -> LDS fp16 (stride 136) -> MFMA accumulate (B-frags from global/L1).
// Epilogue: + cnt[v][t]*bs[t][col], fp16 store to ab.
__global__ __launch_bounds__(256) void k_agg_gemm(
    const unsigned short* __restrict__ hb,
    const int* __restrict__ rowp4, const int* __restrict__ esrc,
    const int* __restrict__ deg4,
    const unsigned short* __restrict__ Wsb,   // 4 * 128*128 fp16 (row-major out x in)
    const float* __restrict__ bs,             // 4 * 128 fp32
    unsigned short* __restrict__ ab) {
    __shared__ unsigned short Ss[128 * 136];
    __shared__ float Bsb[512];

    const int tid = threadIdx.x;
    const int m0 = blockIdx.x * 128;

    Bsb[tid] = bs[tid];
    Bsb[tid + 256] = bs[tid + 256];

    const int r = tid >> 1;          // gather row 0..127
    const int hsel = tid & 1;        // 64-dim half
    const int n = m0 + r;

    const int lane = tid & 63;
    const int w = tid >> 6;
    const int lr = lane & 15;
    const int q = lane >> 4;

    f32x4 acc[2][8];
#pragma unroll
    for (int mt = 0; mt < 2; ++mt)
#pragma unroll
        for (int nt = 0; nt < 8; ++nt) acc[mt][nt] = (f32x4){0.f, 0.f, 0.f, 0.f};

    for (int t = 0; t < 4; ++t) {
        float sacc[64];
#pragma unroll
        for (int j = 0; j < 64; ++j) sacc[j] = 0.f;
        if (n < NN) {
            int beg = rowp4[n * 4 + t], end = rowp4[n * 4 + t + 1];
            for (int i = beg; i < end; ++i) {
                const f16x8* row8 = (const f16x8*)&hb[(size_t)esrc[i] * 128 + hsel * 64];
#pragma unroll
                for (int jj = 0; jj < 8; ++jj) {
                    f16x8 v = row8[jj];
#pragma unroll
                    for (int k = 0; k < 8; ++k) sacc[jj * 8 + k] += (float)v[k];
                }
            }
        }
        __syncthreads();   // prior t's MFMA reads of Ss complete
#pragma unroll
        for (int jj = 0; jj < 8; ++jj) {
            f16x8 hv;
#pragma unroll
            for (int k = 0; k < 8; ++k) hv[k] = (_Float16)sacc[jj * 8 + k];
            *(f16x8*)&Ss[r * 136 + hsel * 64 + jj * 8] = hv;
        }
        __syncthreads();

        const unsigned short* Wt = Wsb + t * 16384;
#pragma unroll
        for (int ks = 0; ks < 4; ++ks) {
            f16x8 af[2];
#pragma unroll
            for (int mt = 0; mt < 2; ++mt)
                af[mt] = *(const f16x8*)&Ss[(w * 32 + mt * 16 + lr) * 136 + ks * 32 + q * 8];
#pragma unroll
            for (int nt = 0; nt < 8; ++nt) {
                f16x8 bf = *(const f16x8*)&Wt[(nt * 16 + lr) * 128 + ks * 32 + q * 8];
#pragma unroll
                for (int mt = 0; mt < 2; ++mt)
                    acc[mt][nt] = __builtin_amdgcn_mfma_f32_16x16x32_f16(
                        af[mt], bf, acc[mt][nt], 0, 0, 0);
            }
        }
    }

    // epilogue: + sum_t cnt*bs, fp16 store
#pragma unroll
    for (int mt = 0; mt < 2; ++mt) {
        int rowbase = m0 + w * 32 + mt * 16 + q * 4;
#pragma unroll
        for (int rr = 0; rr < 4; ++rr) {
            int n2 = rowbase + rr;
            if (n2 < NN) {
                int4 c = *(const int4*)&deg4[n2 * 4];
                unsigned short* arow = ab + (size_t)n2 * 128;
#pragma unroll
                for (int nt = 0; nt < 8; ++nt) {
                    int col = nt * 16 + lr;
                    float v = acc[mt][nt][rr]
                            + c.x * Bsb[col] + c.y * Bsb[128 + col]
                            + c.z * Bsb[256 + col] + c.w * Bsb[384 + col];
                    arow[col] = f2h(v);
                }
            }
        }
    }
}

// ---------------- gates GEMM: O[n, g*128+o] = A_g[n,:] . W_g[o,:] + bias_g[o] --------
// g=0..2: A=ab, W_ih rows (gi). g=3..5: A=hb, W_hh rows (gh). O ld = LDO (768).
__global__ __launch_bounds__(256) void k_gates_gemm(
    const unsigned short* __restrict__ Aab, const unsigned short* __restrict__ Ahb,
    int M,
    const unsigned short* __restrict__ Wih, const unsigned short* __restrict__ Whh,
    const float* __restrict__ bih, const float* __restrict__ bhh,
    unsigned short* __restrict__ C) {
    __shared__ unsigned short As[128 * 136];
    __shared__ unsigned short Bs[128 * 136];

    const int g = blockIdx.y;
    const unsigned short* Ab = (g < 3) ? Aab : Ahb;
    const unsigned short* W  = (g < 3) ? (Wih + (size_t)g * 16384)
                                       : (Whh + (size_t)(g - 3) * 16384);
    const float* bias = (g < 3) ? (bih + g * 128) : (bhh + (g - 3) * 128);
    const int colbase = g * 128;
    const int m0 = blockIdx.x * 128;
    const int tid = threadIdx.x;

    const uint4* A4 = (const uint4*)Ab;
    const uint4* W4 = (const uint4*)W;

#pragma unroll
    for (int i = tid; i < 2048; i += 256) {
        int row = i >> 4, qq = i & 15;
        int nn = m0 + row;
        uint4 va = (nn < M) ? A4[(size_t)nn * 16 + qq] : make_uint4(0u, 0u, 0u, 0u);
        *(uint4*)&As[row * 136 + qq * 8] = va;
        *(uint4*)&Bs[row * 136 + qq * 8] = W4[(size_t)row * 16 + qq];
    }
    __syncthreads();

    const int lane = tid & 63;
    const int w = tid >> 6;
    const int lr = lane & 15;
    const int q = lane >> 4;

    float bv[8];
#pragma unroll
    for (int nt = 0; nt < 8; ++nt) bv[nt] = bias[nt * 16 + lr];

    f32x4 acc[2][8];
#pragma unroll
    for (int mt = 0; mt < 2; ++mt)
#pragma unroll
        for (int nt = 0; nt < 8; ++nt) acc[mt][nt] = (f32x4){0.f, 0.f, 0.f, 0.f};

#pragma unroll
    for (int ks = 0; ks < 4; ++ks) {
        f16x8 af[2];
#pragma unroll
        for (int mt = 0; mt < 2; ++mt)
            af[mt] = *(const f16x8*)&As[(w * 32 + mt * 16 + lr) * 136 + ks * 32 + q * 8];
        f16x8 bfr[8];
#pragma unroll
        for (int nt = 0; nt < 8; ++nt)
            bfr[nt] = *(const f16x8*)&Bs[(nt * 16 + lr) * 136 + ks * 32 + q * 8];
#pragma unroll
        for (int mt = 0; mt < 2; ++mt)
#pragma unroll
            for (int nt = 0; nt < 8; ++nt)
                acc[mt][nt] = __builtin_amdgcn_mfma_f32_16x16x32_f16(
                    af[mt], bfr[nt], acc[mt][nt], 0, 0, 0);
    }

#pragma unroll
    for (int mt = 0; mt < 2; ++mt) {
        int rowbase = m0 + w * 32 + mt * 16 + q * 4;
#pragma unroll
        for (int rr = 0; rr < 4; ++rr) {
            int nn = rowbase + rr;
            if (nn < M) {
                unsigned short* crow = C + (size_t)nn * LDO + colbase;
#pragma unroll
                for (int nt = 0; nt < 8; ++nt)
                    crow[nt * 16 + lr] = f2h(acc[mt][nt][rr] + bv[nt]);
            }
        }
    }
}

// ---------------- fused GRU pointwise (2 dims/thread) ----------------
__global__ void k_gru(const unsigned short* __restrict__ O, float* __restrict__ h,
                      unsigned short* __restrict__ hb) {
    int i = blockIdx.x * 256 + threadIdx.x;
    if (i >= NN * 64) return;
    int n = i >> 6, p = (i & 63) * 2;
    const unsigned short* r = O + (size_t)n * LDO;
    f16x2 ir = *(const f16x2*)&r[p];
    f16x2 iz = *(const f16x2*)&r[128 + p];
    f16x2 in_ = *(const f16x2*)&r[256 + p];
    f16x2 hr = *(const f16x2*)&r[384 + p];
    f16x2 hz = *(const f16x2*)&r[512 + p];
    f16x2 hn = *(const f16x2*)&r[640 + p];
    float2 hv = *(const float2*)&h[(size_t)n * OD + p];
    float2 nh;
    {
        float rg = 1.f / (1.f + __expf(-((float)ir[0] + (float)hr[0])));
        float zg = 1.f / (1.f + __expf(-((float)iz[0] + (float)hz[0])));
        float ng = tanhf((float)in_[0] + rg * (float)hn[0]);
        nh.x = (1.f - zg) * ng + zg * hv.x;
        rg = 1.f / (1.f + __expf(-((float)ir[1] + (float)hr[1])));
        zg = 1.f / (1.f + __expf(-((float)iz[1] + (float)hz[1])));
        ng = tanhf((float)in_[1] + rg * (float)hn[1]);
        nh.y = (1.f - zg) * ng + zg * hv.y;
    }
    *(float2*)&h[(size_t)n * OD + p] = nh;
    f16x2 hb2; hb2[0] = (_Float16)nh.x; hb2[1] = (_Float16)nh.y;
    *(f16x2*)&hb[(size_t)n * OD + p] = hb2;
}

// ---------------- graph readout: register acc over graph-sorted node list ------------
__global__ void k_readout(const float* __restrict__ h, const float* __restrict__ nf,
                          const int* __restrict__ nlist, const int* __restrict__ growp,
                          float* __restrict__ partial) {
    int g = blockIdx.x >> 3, c = blockIdx.x & (RC - 1);
    int d = threadIdx.x;
    int s = growp[g], e = growp[g + 1], len = e - s;
    int i0 = s + (int)((long long)len * c / RC);
    int i1 = s + (int)((long long)len * (c + 1) / RC);
    float acc = 0.f;
    for (int i = i0; i < i1; ++i) {
        int n = nlist[i];
        acc += (d < OD) ? h[(size_t)n * OD + d] : nf[(size_t)n * IND + (d - OD)];
    }
    partial[(size_t)blockIdx.x * 192 + d] = acc;
}

__global__ void k_reduce(const float* __restrict__ partial, float* __restrict__ feats) {
    int i = blockIdx.x * 256 + threadIdx.x;
    if (i >= NG * 192) return;
    int g = i / 192, d = i % 192;
    float s = 0.f;
    for (int c = 0; c < RC; ++c) s += partial[(size_t)(g * RC + c) * 192 + d];
    feats[i] = s;
}

__global__ void k_final(const float* __restrict__ feats, const float* __restrict__ W_cls,
                        const float* __restrict__ b_cls, float* __restrict__ out) {
    int g = threadIdx.x;
    if (g >= NG) return;
    float acc = b_cls[0];
    for (int d = 0; d < 192; ++d) acc += feats[g * 192 + d] * W_cls[d];
    out[g] = 1.f / (1.f + __expf(-acc));
}

extern "C" void kernel_launch(void* const* d_in, const int* in_sizes, int n_in,
                              void* d_out, int out_size, void* d_ws, size_t ws_size,
                              hipStream_t stream) {
    const float* nf    = (const float*)d_in[0];
    const int*   src   = (const int*)d_in[1];
    const int*   dst   = (const int*)d_in[2];
    const int*   et    = (const int*)d_in[3];
    const int*   gid   = (const int*)d_in[4];
    const float* Ws    = (const float*)d_in[5];
    const float* bs    = (const float*)d_in[6];
    const float* W_ih  = (const float*)d_in[7];
    const float* W_hh  = (const float*)d_in[8];
    const float* b_ih  = (const float*)d_in[9];
    const float* b_hh  = (const float*)d_in[10];
    const float* W_cls = (const float*)d_in[11];
    const float* b_cls = (const float*)d_in[12];
    float* out = (float*)d_out;

    char* ws = (char*)d_ws;
    size_t off = 0;
    auto alloc = [&](size_t bytes) -> void* {
        off = (off + 255) & ~(size_t)255;
        void* p = ws + off;
        off += bytes;
        return p;
    };
    float*          h    = (float*)alloc((size_t)NN * OD * 4);              // 25.6 MB
    unsigned short* O    = (unsigned short*)alloc((size_t)NN * LDO * 2);    // 76.8 MB
    unsigned short* hb   = (unsigned short*)alloc((size_t)NN * OD * 2);     // 12.8 MB
    unsigned short* ab   = (unsigned short*)alloc((size_t)NN * OD * 2);     // 12.8 MB
    int*   deg4    = (int*)alloc((size_t)NN4 * 4);
    int*   rowp4   = (int*)alloc((size_t)(NN4 + 1) * 4);
    int*   cursor4 = (int*)alloc((size_t)NN4 * 4);
    int*   esrc    = (int*)alloc((size_t)NE * 4);
    int*   bsum    = (int*)alloc(256 * 4);
    int*   gdeg    = (int*)alloc(NG * 4);
    int*   growp   = (int*)alloc((NG + 1) * 4);
    int*   gcur    = (int*)alloc(NG * 4);
    int*   nlist   = (int*)alloc((size_t)NN * 4);
    float* feats   = (float*)alloc((size_t)NG * 192 * 4);
    unsigned short* wsb  = (unsigned short*)alloc((size_t)4 * 16384 * 2);
    unsigned short* wihb = (unsigned short*)alloc((size_t)3 * 16384 * 2);
    unsigned short* whhb = (unsigned short*)alloc((size_t)3 * 16384 * 2);
    (void)ws_size; (void)in_sizes; (void)n_in; (void)out_size;

    // readout partials alias the (dead-by-then) O buffer: 512*192*4 = 393 KB << 76.8 MB
    float* partial = (float*)O;

    hipMemsetAsync(deg4, 0, (size_t)NN4 * 4, stream);
    hipMemsetAsync(gdeg, 0, NG * 4, stream);

    k_cvt<<<(4 * 16384 + 255) / 256, 256, 0, stream>>>(Ws, wsb, 4 * 16384);
    k_cvt<<<(3 * 16384 + 255) / 256, 256, 0, stream>>>(W_ih, wihb, 3 * 16384);
    k_cvt<<<(3 * 16384 + 255) / 256, 256, 0, stream>>>(W_hh, whhb, 3 * 16384);

    k_init_h<<<(NN * OD + 255) / 256, 256, 0, stream>>>(nf, h, hb);

    // (dst, etype) CSR
    k_count<<<(NE + 255) / 256, 256, 0, stream>>>(dst, et, deg4);
    const int nb4 = (NN4 + 1023) / 1024;   // 196
    k_scan1<<<nb4, 1024, 0, stream>>>(deg4, rowp4, bsum, NN4);
    k_scan2<<<1, 256, 0, stream>>>(bsum, nb4);
    k_scan3<<<(NN4 + 255) / 256, 256, 0, stream>>>(deg4, bsum, rowp4, cursor4, NN4);
    k_fill<<<(NE + 255) / 256, 256, 0, stream>>>(src, dst, et, cursor4, esrc);

    // graph CSR (readout)
    const int nbn = (NN + 1023) / 1024;    // 49
    k_gcount<<<nbn, 1024, 0, stream>>>(gid, gdeg);
    k_gscan<<<1, NG, 0, stream>>>(gdeg, growp, gcur);
    k_gfill<<<nbn, 1024, 0, stream>>>(gid, gcur, nlist);

    const int mt = (NN + 127) / 128;   // 391 node tiles
    for (int s = 0; s < 8; ++s) {
        k_agg_gemm<<<mt, 256, 0, stream>>>(hb, rowp4, esrc, deg4, wsb, bs, ab);
        k_gates_gemm<<<dim3(mt, 6), 256, 0, stream>>>(ab, hb, NN, wihb, whhb,
                                                      b_ih, b_hh, O);
        k_gru<<<(NN * 64 + 255) / 256, 256, 0, stream>>>(O, h, hb);
    }

    k_readout<<<NG * RC, 192, 0, stream>>>(h, nf, nlist, growp, partial);
    k_reduce<<<(NG * 192 + 255) / 256, 256, 0, stream>>>(partial, feats);
    k_final<<<1, 64, 0, stream>>>(feats, W_cls, b_cls, out);
}